// Round 1
// baseline (1353.598 us; speedup 1.0000x reference)
//
#include <hip/hip_runtime.h>
#include <hip/hip_bf16.h>
#include <math.h>

// Shapes: B=8, S=2048, D=4096, H=8, DH=512, AD=7, TD=32, HID=256, NBLK=3
// All inputs/outputs fp32.

#define DEV __device__ __forceinline__

DEV float warp_sum64(float v) {
    for (int o = 32; o > 0; o >>= 1) v += __shfl_down(v, o, 64);
    return v;
}

DEV float block_sum256(float v, float* sc) { // sc[4] shared
    v = warp_sum64(v);
    __syncthreads();
    if ((threadIdx.x & 63) == 0) sc[threadIdx.x >> 6] = v;
    __syncthreads();
    return sc[0] + sc[1] + sc[2] + sc[3];
}

DEV float block_max256(float v, float* sc) {
    for (int o = 32; o > 0; o >>= 1) v = fmaxf(v, __shfl_down(v, o, 64));
    __syncthreads();
    if ((threadIdx.x & 63) == 0) sc[threadIdx.x >> 6] = v;
    __syncthreads();
    return fmaxf(fmaxf(sc[0], sc[1]), fmaxf(sc[2], sc[3]));
}

DEV float swish_f(float x) { return x / (1.f + expf(-x)); }
DEV float gelu_f(float x) { return 0.5f * x * (1.f + erff(x * 0.70710678118654752f)); }

// ---------------------------------------------------------------------------
// Generic chunked GEMV: out_part[ic][NB][J] = in[NB rows, chunk of I] @ W[I,J]
// ---------------------------------------------------------------------------
template <int NB, int VEC>
__global__ __launch_bounds__(256) void gemv_part_kernel(
    const float* __restrict__ in, const float* __restrict__ W,
    float* __restrict__ part, int I, int J, int chunk) {
    extern __shared__ float lds[]; // NB * chunk
    int tid = threadIdx.x;
    int jb = blockIdx.x, ic = blockIdx.y;
    int i0 = ic * chunk;
    int cnt = min(chunk, I - i0);
    for (int idx = tid; idx < NB * cnt; idx += 256) {
        int b = idx / cnt, ii = idx - b * cnt;
        lds[b * chunk + ii] = in[(size_t)b * I + i0 + ii];
    }
    __syncthreads();
    int j = (jb * 256 + tid) * VEC;
    float acc[NB][VEC];
#pragma unroll
    for (int b = 0; b < NB; b++)
#pragma unroll
        for (int k = 0; k < VEC; k++) acc[b][k] = 0.f;
    int ii = 0;
    for (; ii + 4 <= cnt; ii += 4) {
        float w[4][VEC];
#pragma unroll
        for (int u = 0; u < 4; u++) {
            const float* wp = W + (size_t)(i0 + ii + u) * J + j;
            if constexpr (VEC == 4) {
                float4 t = *(const float4*)wp;
                w[u][0] = t.x; w[u][1] = t.y; w[u][2] = t.z; w[u][3] = t.w;
            } else {
                w[u][0] = wp[0];
            }
        }
#pragma unroll
        for (int u = 0; u < 4; u++)
#pragma unroll
            for (int b = 0; b < NB; b++) {
                float v = lds[b * chunk + ii + u];
#pragma unroll
                for (int k = 0; k < VEC; k++) acc[b][k] = fmaf(v, w[u][k], acc[b][k]);
            }
    }
    for (; ii < cnt; ii++) {
        const float* wp = W + (size_t)(i0 + ii) * J + j;
#pragma unroll
        for (int b = 0; b < NB; b++) {
            float v = lds[b * chunk + ii];
#pragma unroll
            for (int k = 0; k < VEC; k++) acc[b][k] = fmaf(v, wp[k], acc[b][k]);
        }
    }
#pragma unroll
    for (int b = 0; b < NB; b++) {
        float* pp = part + ((size_t)ic * NB + b) * J + j;
        if constexpr (VEC == 4) {
            float4 o; o.x = acc[b][0]; o.y = acc[b][1]; o.z = acc[b][2]; o.w = acc[b][3];
            *(float4*)pp = o;
        } else {
            pp[0] = acc[b][0];
        }
    }
}

// ---------------------------------------------------------------------------
// Reduce partials: out[idx] = act( sum_c part[c][idx] + bias[j] + res[idx] )
// act: 0 none, 1 gelu(exact), 2 swish
// ---------------------------------------------------------------------------
__global__ __launch_bounds__(256) void reduce_kernel(
    const float* __restrict__ part, const float* __restrict__ bias,
    const float* __restrict__ res, float* __restrict__ out,
    int NBJ, int J, int nc, int act) {
    for (int idx = blockIdx.x * 256 + threadIdx.x; idx < NBJ; idx += gridDim.x * 256) {
        float s = 0.f;
        for (int c = 0; c < nc; c++) s += part[(size_t)c * NBJ + idx];
        int j = idx % J;
        if (bias) s += bias[j];
        if (res) s += res[idx];
        if (act == 1) s = gelu_f(s);
        else if (act == 2) s = swish_f(s);
        out[idx] = s;
    }
}

// ---------------------------------------------------------------------------
// qw[h][i] = sum_{c<512} q[h*512+c] * wk[i][h*512+c]   (one wave per (h,i))
// ---------------------------------------------------------------------------
__global__ __launch_bounds__(256) void qw_kernel(
    const float* __restrict__ q, const float* __restrict__ wk,
    float* __restrict__ qw) {
    int gw = blockIdx.x * 4 + (threadIdx.x >> 6); // 0..32767
    int lane = threadIdx.x & 63;
    int h = gw >> 12, i = gw & 4095;
    const float* wrow = wk + (size_t)i * 4096 + h * 512;
    const float* qrow = q + h * 512;
    float acc = 0.f;
#pragma unroll
    for (int k = 0; k < 8; k++) acc = fmaf(qrow[lane + 64 * k], wrow[lane + 64 * k], acc);
    acc = warp_sum64(acc);
    if (lane == 0) qw[(size_t)h * 4096 + i] = acc;
}

// ---------------------------------------------------------------------------
// scores_part[cc][b][h][s] = llm[b,s, cc*1024 : +1024] . qw[h, same range]
// grid (1024 row-chunks of 16 rows, 4 c-chunks); block 256 = 4 waves x 4 rows
// ---------------------------------------------------------------------------
__global__ __launch_bounds__(256) void scores_kernel(
    const float* __restrict__ llm, const float* __restrict__ qw,
    float* __restrict__ part) {
    __shared__ float qlds[8192]; // 8 heads x 1024 c, 32 KB
    int tid = threadIdx.x;
    int rc = blockIdx.x, cc = blockIdx.y;
    for (int idx = tid; idx < 8192; idx += 256)
        qlds[idx] = qw[(size_t)(idx >> 10) * 4096 + cc * 1024 + (idx & 1023)];
    __syncthreads();
    int wid = tid >> 6, lane = tid & 63;
    int row0 = rc * 16 + wid * 4;
    const float* base = llm + (size_t)row0 * 4096 + cc * 1024 + lane * 4;
    float acc[4][8] = {};
    for (int it = 0; it < 4; ++it) {
        float4 lv[4];
#pragma unroll
        for (int r = 0; r < 4; r++) lv[r] = *(const float4*)(base + (size_t)r * 4096 + it * 256);
#pragma unroll
        for (int h = 0; h < 8; h++) {
            float4 q4 = *(const float4*)&qlds[h * 1024 + it * 256 + lane * 4];
#pragma unroll
            for (int r = 0; r < 4; r++)
                acc[r][h] += lv[r].x * q4.x + lv[r].y * q4.y + lv[r].z * q4.z + lv[r].w * q4.w;
        }
    }
#pragma unroll
    for (int r = 0; r < 4; r++)
#pragma unroll
        for (int h = 0; h < 8; h++) acc[r][h] = warp_sum64(acc[r][h]);
    if (lane == 0) {
#pragma unroll
        for (int r = 0; r < 4; r++) {
            int row = row0 + r;
            int b = row >> 11, s = row & 2047;
#pragma unroll
            for (int h = 0; h < 8; h++)
                part[((size_t)(cc * 8 + b) * 8 + h) * 2048 + s] = acc[r][h];
        }
    }
}

// ---------------------------------------------------------------------------
// softmax over s (2048) per (b,h); input = 4 c-chunk partials, scale 1/sqrt(512)
// ---------------------------------------------------------------------------
__global__ __launch_bounds__(256) void softmax_kernel(
    const float* __restrict__ part, float* __restrict__ attn) {
    __shared__ float sc[4];
    int bh = blockIdx.x, tid = threadIdx.x;
    float v[8];
    float mx = -1e30f;
#pragma unroll
    for (int k = 0; k < 8; k++) {
        int s = tid + k * 256;
        float x = 0.f;
        for (int cc = 0; cc < 4; cc++) x += part[((size_t)(cc * 64 + bh)) * 2048 + s];
        x *= 0.04419417382415922f; // 1/sqrt(512)
        v[k] = x;
        mx = fmaxf(mx, x);
    }
    float M = block_max256(mx, sc);
    float sum = 0.f;
#pragma unroll
    for (int k = 0; k < 8; k++) { v[k] = expf(v[k] - M); sum += v[k]; }
    float Sv = block_sum256(sum, sc);
    float inv = 1.f / Sv;
#pragma unroll
    for (int k = 0; k < 8; k++) attn[(size_t)bh * 2048 + tid + k * 256] = v[k] * inv;
}

// ---------------------------------------------------------------------------
// pooled_part[sc][b][h][j] = sum_{s in chunk of 128} attn[b,h,s] * llm[b,s,j]
// grid (4 jb, 16 sc, 8 b)
// ---------------------------------------------------------------------------
__global__ __launch_bounds__(256) void pooled_kernel(
    const float* __restrict__ llm, const float* __restrict__ attn,
    float* __restrict__ part) {
    __shared__ float alds[1024]; // 8 h x 128 s
    int tid = threadIdx.x;
    int jb = blockIdx.x, sc = blockIdx.y, b = blockIdx.z;
    for (int idx = tid; idx < 1024; idx += 256) {
        int h = idx >> 7, sl = idx & 127;
        alds[idx] = attn[((size_t)(b * 8 + h)) * 2048 + sc * 128 + sl];
    }
    __syncthreads();
    int j = jb * 1024 + tid * 4;
    const float* lbase = llm + ((size_t)(b * 2048 + sc * 128)) * 4096 + j;
    float acc[8][4] = {};
    for (int si = 0; si < 128; si += 4) {
        float4 lv[4];
#pragma unroll
        for (int u = 0; u < 4; u++) lv[u] = *(const float4*)(lbase + (size_t)(si + u) * 4096);
#pragma unroll
        for (int u = 0; u < 4; u++)
#pragma unroll
            for (int h = 0; h < 8; h++) {
                float a = alds[h * 128 + si + u];
                acc[h][0] = fmaf(a, lv[u].x, acc[h][0]);
                acc[h][1] = fmaf(a, lv[u].y, acc[h][1]);
                acc[h][2] = fmaf(a, lv[u].z, acc[h][2]);
                acc[h][3] = fmaf(a, lv[u].w, acc[h][3]);
            }
    }
#pragma unroll
    for (int h = 0; h < 8; h++) {
        float4 o; o.x = acc[h][0]; o.y = acc[h][1]; o.z = acc[h][2]; o.w = acc[h][3];
        *(float4*)(part + ((size_t)(sc * 8 + b) * 8 + h) * 4096 + j) = o;
    }
}

// ---------------------------------------------------------------------------
// ctx_part[ic][b][j] = sum_{i in chunk 64} pooled[b, h(j), i] * wv[i][j]
// grid (4 jb, 64 ic); h(j) = j/512, block covers 2 heads
// ---------------------------------------------------------------------------
__global__ __launch_bounds__(256) void ctx_gemv_kernel(
    const float* __restrict__ pooled, const float* __restrict__ wv,
    float* __restrict__ part) {
    __shared__ float plds[1024]; // [b][hh][ii] = 8*2*64
    int tid = threadIdx.x, jb = blockIdx.x, ic = blockIdx.y;
    int i0 = ic * 64, h0 = jb * 2;
    for (int idx = tid; idx < 1024; idx += 256) {
        int b = idx >> 7, r = idx & 127, hh = r >> 6, ii = r & 63;
        plds[(b * 2 + hh) * 64 + ii] = pooled[((size_t)(b * 8 + h0 + hh)) * 4096 + i0 + ii];
    }
    __syncthreads();
    int j = jb * 1024 + tid * 4;
    int hh = tid >> 7;
    float acc[8][4] = {};
    for (int ii = 0; ii < 64; ii += 4) {
        float4 w[4];
#pragma unroll
        for (int u = 0; u < 4; u++) w[u] = *(const float4*)(wv + (size_t)(i0 + ii + u) * 4096 + j);
#pragma unroll
        for (int u = 0; u < 4; u++)
#pragma unroll
            for (int b = 0; b < 8; b++) {
                float v = plds[(b * 2 + hh) * 64 + ii + u];
                acc[b][0] = fmaf(v, w[u].x, acc[b][0]);
                acc[b][1] = fmaf(v, w[u].y, acc[b][1]);
                acc[b][2] = fmaf(v, w[u].z, acc[b][2]);
                acc[b][3] = fmaf(v, w[u].w, acc[b][3]);
            }
    }
#pragma unroll
    for (int b = 0; b < 8; b++) {
        float4 o; o.x = acc[b][0]; o.y = acc[b][1]; o.z = acc[b][2]; o.w = acc[b][3];
        *(float4*)(part + ((size_t)ic * 8 + b) * 4096 + j) = o;
    }
}

// ---------------------------------------------------------------------------
// LayerNorm: out[b, :N] = (x - mean) * rsqrt(var + 1e-5) * g + be
// ---------------------------------------------------------------------------
__global__ __launch_bounds__(256) void ln_kernel(
    const float* __restrict__ x, const float* __restrict__ g,
    const float* __restrict__ be, float* __restrict__ out, int N) {
    __shared__ float sc[4];
    int b = blockIdx.x, tid = threadIdx.x;
    const float* xb = x + (size_t)b * N;
    float s = 0.f, s2 = 0.f;
    for (int i = tid; i < N; i += 256) { float v = xb[i]; s += v; s2 += v * v; }
    s = block_sum256(s, sc);
    s2 = block_sum256(s2, sc);
    float mean = s / N;
    float var = s2 / N - mean * mean;
    float rstd = rsqrtf(var + 1e-5f);
    float* ob = out + (size_t)b * N;
    for (int i = tid; i < N; i += 256) {
        float v = xb[i];
        ob[i] = (v - mean) * rstd * g[i] + be[i];
    }
}

// ---------------------------------------------------------------------------
// Fourier features + cond MLP (tiny, 1 block)
// ---------------------------------------------------------------------------
__global__ __launch_bounds__(256) void cond_kernel(
    const float* __restrict__ time, const float* __restrict__ four_w,
    const float* __restrict__ w1, const float* __restrict__ b1,
    const float* __restrict__ w2, const float* __restrict__ b2,
    float* __restrict__ cond) {
    __shared__ float ffl[256]; // [b][32]
    __shared__ float c1[512];  // [b][64]
    int tid = threadIdx.x;
    {
        int b = tid >> 5, jj = tid & 31;
        float f = 6.283185307179586f * time[b] * four_w[jj & 15];
        ffl[tid] = (jj < 16) ? cosf(f) : sinf(f);
    }
    __syncthreads();
    for (int idx = tid; idx < 512; idx += 256) {
        int b = idx >> 6, jj = idx & 63;
        float s = b1[jj];
        for (int i = 0; i < 32; i++) s = fmaf(ffl[b * 32 + i], w1[i * 64 + jj], s);
        c1[idx] = swish_f(s);
    }
    __syncthreads();
    {
        int b = tid >> 5, jj = tid & 31;
        float s = b2[jj];
        for (int i = 0; i < 64; i++) s = fmaf(c1[b * 64 + i], w2[i * 32 + jj], s);
        cond[b * 32 + jj] = s;
    }
}

// ---------------------------------------------------------------------------
// rin projection with concat input [cond(32), pooled_final(4096), noisy(7)]
// part[ic][b][256]; grid 65 blocks, chunk 64
// ---------------------------------------------------------------------------
__global__ __launch_bounds__(256) void rin_gemv_kernel(
    const float* __restrict__ cond, const float* __restrict__ pfinal,
    const float* __restrict__ noisy, const float* __restrict__ W,
    float* __restrict__ part) {
    __shared__ float lds[512]; // 8 x 64
    int tid = threadIdx.x, ic = blockIdx.x;
    int i0 = ic * 64;
    int cnt = min(64, 4135 - i0);
    for (int idx = tid; idx < 8 * cnt; idx += 256) {
        int b = idx / cnt, ii = idx - b * cnt;
        int i = i0 + ii;
        float v;
        if (i < 32) v = cond[b * 32 + i];
        else if (i < 4128) v = pfinal[(size_t)b * 4096 + i - 32];
        else v = noisy[b * 7 + i - 4128];
        lds[b * 64 + ii] = v;
    }
    __syncthreads();
    int j = tid;
    float acc[8] = {};
#pragma unroll 4
    for (int ii = 0; ii < cnt; ii++) {
        float w = W[(size_t)(i0 + ii) * 256 + j];
#pragma unroll
        for (int b = 0; b < 8; b++) acc[b] = fmaf(lds[b * 64 + ii], w, acc[b]);
    }
#pragma unroll
    for (int b = 0; b < 8; b++) part[((size_t)ic * 8 + b) * 256 + j] = acc[b];
}

// ---------------------------------------------------------------------------
// final: out[b][a] = swish(x3[b,:]) . out_w[:,a] + out_b[a]   (1 block)
// ---------------------------------------------------------------------------
__global__ __launch_bounds__(256) void final_kernel(
    const float* __restrict__ x3, const float* __restrict__ out_w,
    const float* __restrict__ out_b, float* __restrict__ out) {
    __shared__ float sw[2048];
    int tid = threadIdx.x;
    for (int idx = tid; idx < 2048; idx += 256) sw[idx] = swish_f(x3[idx]);
    __syncthreads();
    if (tid < 56) {
        int b = tid / 7, a = tid - b * 7;
        float s = out_b[a];
        for (int i = 0; i < 256; i++) s = fmaf(sw[b * 256 + i], out_w[i * 7 + a], s);
        out[tid] = s;
    }
}

// ---------------------------------------------------------------------------
extern "C" void kernel_launch(void* const* d_in, const int* in_sizes, int n_in,
                              void* d_out, int out_size, void* d_ws, size_t ws_size,
                              hipStream_t stream) {
    const float* llm     = (const float*)d_in[0];
    const float* time_   = (const float*)d_in[1];
    const float* noisy   = (const float*)d_in[2];
    const float* probe   = (const float*)d_in[3];
    const float* wq      = (const float*)d_in[4];
    const float* wk      = (const float*)d_in[5];
    const float* wv      = (const float*)d_in[6];
    const float* bq      = (const float*)d_in[7];
    // d_in[8] = bk: exactly cancels in softmax (constant per (b,h) row) — unused.
    const float* bv      = (const float*)d_in[9];
    const float* wo      = (const float*)d_in[10];
    const float* bo      = (const float*)d_in[11];
    const float* ln_g    = (const float*)d_in[12];
    const float* ln_b    = (const float*)d_in[13];
    const float* mlp_w1  = (const float*)d_in[14];
    const float* mlp_b1  = (const float*)d_in[15];
    const float* mlp_w2  = (const float*)d_in[16];
    const float* mlp_b2  = (const float*)d_in[17];
    const float* four_w  = (const float*)d_in[18];
    const float* cond_w1 = (const float*)d_in[19];
    const float* cond_b1 = (const float*)d_in[20];
    const float* cond_w2 = (const float*)d_in[21];
    const float* cond_b2 = (const float*)d_in[22];
    const float* rin_w   = (const float*)d_in[23];
    const float* rin_b   = (const float*)d_in[24];
    const float* bln_g   = (const float*)d_in[25];
    const float* bln_b   = (const float*)d_in[26];
    const float* bw1     = (const float*)d_in[27];
    const float* bb1     = (const float*)d_in[28];
    const float* bw2     = (const float*)d_in[29];
    const float* bb2     = (const float*)d_in[30];
    const float* out_w   = (const float*)d_in[31];
    const float* out_b   = (const float*)d_in[32];

    float* ws = (float*)d_ws;
    const size_t A = (size_t)4 * 1024 * 1024; // 16 MB partial arena (floats)
    float* arena    = ws;
    float* q        = ws + A;            // 4096
    float* qw       = q + 4096;          // 8*4096
    float* attn     = qw + 32768;        // 8*8*2048
    float* pooled   = attn + 131072;     // 8*8*4096
    float* ctx      = pooled + 262144;   // 8*4096
    float* attn_out = ctx + 32768;       // 8*4096
    float* y        = attn_out + 32768;  // 8*4096
    float* h1a      = y + 32768;         // 8*16384
    float* pfinal   = h1a + 131072;      // 8*4096
    float* cond     = pfinal + 32768;    // 8*32
    float* x0       = cond + 256;        // 8*256
    float* xln      = x0 + 2048;
    float* g1a      = xln + 2048;        // 8*1024
    float* x1       = g1a + 8192;
    float* x2       = x1 + 2048;
    float* x3       = x2 + 2048;

    // ---- MAPHead ----
    // q = probe @ wq + bq   (batch-independent)
    gemv_part_kernel<1, 4><<<dim3(4, 64), 256, 1 * 64 * 4, stream>>>(probe, wq, arena, 4096, 4096, 64);
    reduce_kernel<<<16, 256, 0, stream>>>(arena, bq, nullptr, q, 4096, 4096, 64, 0);
    // qw[h][i] = q_h . wk[i, head h cols]
    qw_kernel<<<8192, 256, 0, stream>>>(q, wk, qw);
    // scores (llm pass 1)
    scores_kernel<<<dim3(1024, 4), 256, 0, stream>>>(llm, qw, arena);
    softmax_kernel<<<64, 256, 0, stream>>>(arena, attn);
    // pooled[b,h,:] = sum_s attn * llm (llm pass 2)
    pooled_kernel<<<dim3(4, 16, 8), 256, 0, stream>>>(llm, attn, arena);
    reduce_kernel<<<256, 256, 0, stream>>>(arena, nullptr, nullptr, pooled, 262144, 4096, 16, 0);
    // ctx = pooled @ wv + bv
    ctx_gemv_kernel<<<dim3(4, 64), 256, 0, stream>>>(pooled, wv, arena);
    reduce_kernel<<<128, 256, 0, stream>>>(arena, bv, nullptr, ctx, 32768, 4096, 64, 0);
    // attn_out = ctx @ wo + bo
    gemv_part_kernel<8, 4><<<dim3(4, 64), 256, 8 * 64 * 4, stream>>>(ctx, wo, arena, 4096, 4096, 64);
    reduce_kernel<<<128, 256, 0, stream>>>(arena, bo, nullptr, attn_out, 32768, 4096, 64, 0);
    // y = LN(attn_out); h = gelu(y@w1+b1)@w2+b2; pfinal = attn_out + h
    ln_kernel<<<8, 256, 0, stream>>>(attn_out, ln_g, ln_b, y, 4096);
    gemv_part_kernel<8, 4><<<dim3(16, 16), 256, 8 * 256 * 4, stream>>>(y, mlp_w1, arena, 4096, 16384, 256);
    reduce_kernel<<<256, 256, 0, stream>>>(arena, mlp_b1, nullptr, h1a, 131072, 16384, 16, 1);
    gemv_part_kernel<8, 4><<<dim3(4, 64), 256, 8 * 256 * 4, stream>>>(h1a, mlp_w2, arena, 16384, 4096, 256);
    reduce_kernel<<<128, 256, 0, stream>>>(arena, mlp_b2, attn_out, pfinal, 32768, 4096, 64, 0);

    // ---- diffusion tail ----
    cond_kernel<<<1, 256, 0, stream>>>(time_, four_w, cond_w1, cond_b1, cond_w2, cond_b2, cond);
    rin_gemv_kernel<<<65, 256, 0, stream>>>(cond, pfinal, noisy, rin_w, arena);
    reduce_kernel<<<8, 256, 0, stream>>>(arena, rin_b, nullptr, x0, 2048, 256, 65, 0);

    float* xs[4] = {x0, x1, x2, x3};
    for (int i = 0; i < 3; i++) {
        ln_kernel<<<8, 256, 0, stream>>>(xs[i], bln_g + i * 256, bln_b + i * 256, xln, 256);
        gemv_part_kernel<8, 1><<<dim3(4, 4), 256, 8 * 64 * 4, stream>>>(
            xln, bw1 + (size_t)i * 256 * 1024, arena, 256, 1024, 64);
        reduce_kernel<<<32, 256, 0, stream>>>(arena, bb1 + i * 1024, nullptr, g1a, 8192, 1024, 4, 2);
        gemv_part_kernel<8, 1><<<dim3(1, 16), 256, 8 * 64 * 4, stream>>>(
            g1a, bw2 + (size_t)i * 1024 * 256, arena, 1024, 256, 64);
        reduce_kernel<<<8, 256, 0, stream>>>(arena, bb2 + i * 256, xs[i], xs[i + 1], 2048, 256, 16, 0);
    }
    final_kernel<<<1, 256, 0, stream>>>(x3, out_w, out_b, (float*)d_out);
}

// Round 2
// 1301.778 us; speedup vs baseline: 1.0398x; 1.0398x over previous
//
#include <hip/hip_runtime.h>
#include <hip/hip_bf16.h>
#include <math.h>

// Shapes: B=8, S=2048, D=4096, H=8, DH=512, AD=7, TD=32, HID=256, NBLK=3
// All inputs/outputs fp32. B=8 makes every matmul a batched GEMV -> HBM-bound
// on weights + llm: floor ~1.34 GB ~= 215 us @ 6.3 TB/s.

#define DEV __device__ __forceinline__

DEV float warp_sum64(float v) {
    for (int o = 32; o > 0; o >>= 1) v += __shfl_down(v, o, 64);
    return v;
}

DEV float block_sum256(float v, float* sc) { // sc[4] shared
    v = warp_sum64(v);
    __syncthreads();
    if ((threadIdx.x & 63) == 0) sc[threadIdx.x >> 6] = v;
    __syncthreads();
    return sc[0] + sc[1] + sc[2] + sc[3];
}

DEV float block_max256(float v, float* sc) {
    for (int o = 32; o > 0; o >>= 1) v = fmaxf(v, __shfl_down(v, o, 64));
    __syncthreads();
    if ((threadIdx.x & 63) == 0) sc[threadIdx.x >> 6] = v;
    __syncthreads();
    return fmaxf(fmaxf(sc[0], sc[1]), fmaxf(sc[2], sc[3]));
}

DEV float swish_f(float x) { return x / (1.f + expf(-x)); }
DEV float gelu_f(float x) { return 0.5f * x * (1.f + erff(x * 0.70710678118654752f)); }

// ---------------------------------------------------------------------------
// Chunked GEMV: part[ic][NB][J] = in[NB rows, chunk ic of I] @ W[I,J]
// chunk % 8 == 0 and I % chunk == 0 required. VEC=4 columns/thread.
// ---------------------------------------------------------------------------
template <int NB>
__global__ __launch_bounds__(256) void gemvp_k(
    const float* __restrict__ in, const float* __restrict__ W,
    float* __restrict__ part, int I, int J, int chunk) {
    extern __shared__ float lds[]; // NB * chunk
    int tid = threadIdx.x;
    int jb = blockIdx.x, ic = blockIdx.y;
    int i0 = ic * chunk;
    for (int idx = tid; idx < NB * chunk; idx += 256) {
        int b = idx / chunk, ii = idx - b * chunk;
        lds[idx] = in[(size_t)b * I + i0 + ii];
    }
    __syncthreads();
    int j = (jb * 256 + tid) * 4;
    float acc[NB][4];
#pragma unroll
    for (int b = 0; b < NB; b++)
#pragma unroll
        for (int k = 0; k < 4; k++) acc[b][k] = 0.f;
    const float* wbase = W + (size_t)i0 * J + j;
    for (int ii = 0; ii < chunk; ii += 8) {
        float4 w[8];
#pragma unroll
        for (int u = 0; u < 8; u++) w[u] = *(const float4*)(wbase + (size_t)(ii + u) * J);
#pragma unroll
        for (int u = 0; u < 8; u++)
#pragma unroll
            for (int b = 0; b < NB; b++) {
                float v = lds[b * chunk + ii + u];
                acc[b][0] = fmaf(v, w[u].x, acc[b][0]);
                acc[b][1] = fmaf(v, w[u].y, acc[b][1]);
                acc[b][2] = fmaf(v, w[u].z, acc[b][2]);
                acc[b][3] = fmaf(v, w[u].w, acc[b][3]);
            }
    }
#pragma unroll
    for (int b = 0; b < NB; b++) {
        float4 o; o.x = acc[b][0]; o.y = acc[b][1]; o.z = acc[b][2]; o.w = acc[b][3];
        *(float4*)(part + ((size_t)ic * NB + b) * J + j) = o;
    }
}

// ---------------------------------------------------------------------------
// Reduce partials: out[idx] = act( sum_c part[c][idx] + bias[j] + res[idx] )
// act: 0 none, 1 gelu(exact), 2 swish
// ---------------------------------------------------------------------------
__global__ __launch_bounds__(256) void reduce_k(
    const float* __restrict__ part, const float* __restrict__ bias,
    const float* __restrict__ res, float* __restrict__ out,
    int NBJ, int J, int nc, int act) {
    for (int idx = blockIdx.x * 256 + threadIdx.x; idx < NBJ; idx += gridDim.x * 256) {
        float s = 0.f;
        for (int c = 0; c < nc; c++) s += part[(size_t)c * NBJ + idx];
        int j = idx % J;
        if (bias) s += bias[j];
        if (res) s += res[idx];
        if (act == 1) s = gelu_f(s);
        else if (act == 2) s = swish_f(s);
        out[idx] = s;
    }
}

// ---------------------------------------------------------------------------
// qw[h][i] = sum_{c<512} q[h*512+c] * wk[i][h*512+c]   (one wave per (h,i))
// bk dropped: constant per (b,h) across s -> cancels exactly in softmax.
// ---------------------------------------------------------------------------
__global__ __launch_bounds__(256) void qw_k(
    const float* __restrict__ q, const float* __restrict__ wk,
    float* __restrict__ qw) {
    int gw = blockIdx.x * 4 + (threadIdx.x >> 6); // 0..32767
    int lane = threadIdx.x & 63;
    int h = gw >> 12, i = gw & 4095;
    const float* wrow = wk + (size_t)i * 4096 + h * 512;
    const float* qrow = q + h * 512;
    float acc = 0.f;
#pragma unroll
    for (int k = 0; k < 8; k++) acc = fmaf(qrow[lane + 64 * k], wrow[lane + 64 * k], acc);
    acc = warp_sum64(acc);
    if (lane == 0) qw[(size_t)h * 4096 + i] = acc;
}

// ---------------------------------------------------------------------------
// scores_part[cc][b][h][s] = llm[b,s, cc*1024:+1024] . qw[h, same range]
// grid (1024 row-chunks of 16 rows, 4 c-chunks); block 256 = 4 waves x 4 rows
// ---------------------------------------------------------------------------
__global__ __launch_bounds__(256) void scores_k(
    const float* __restrict__ llm, const float* __restrict__ qw,
    float* __restrict__ part) {
    __shared__ float qlds[8192]; // 8 heads x 1024 c, 32 KB
    int tid = threadIdx.x;
    int rc = blockIdx.x, cc = blockIdx.y;
    for (int idx = tid; idx < 8192; idx += 256)
        qlds[idx] = qw[(size_t)(idx >> 10) * 4096 + cc * 1024 + (idx & 1023)];
    __syncthreads();
    int wid = tid >> 6, lane = tid & 63;
    int row0 = rc * 16 + wid * 4;
    const float* base = llm + (size_t)row0 * 4096 + cc * 1024 + lane * 4;
    float acc[4][8] = {};
    for (int it = 0; it < 4; ++it) {
        float4 lv[4];
#pragma unroll
        for (int r = 0; r < 4; r++) lv[r] = *(const float4*)(base + (size_t)r * 4096 + it * 256);
#pragma unroll
        for (int h = 0; h < 8; h++) {
            float4 q4 = *(const float4*)&qlds[h * 1024 + it * 256 + lane * 4];
#pragma unroll
            for (int r = 0; r < 4; r++)
                acc[r][h] += lv[r].x * q4.x + lv[r].y * q4.y + lv[r].z * q4.z + lv[r].w * q4.w;
        }
    }
#pragma unroll
    for (int r = 0; r < 4; r++)
#pragma unroll
        for (int h = 0; h < 8; h++) acc[r][h] = warp_sum64(acc[r][h]);
    if (lane == 0) {
#pragma unroll
        for (int r = 0; r < 4; r++) {
            int row = row0 + r;
            int b = row >> 11, s = row & 2047;
#pragma unroll
            for (int h = 0; h < 8; h++)
                part[((size_t)(cc * 8 + b) * 8 + h) * 2048 + s] = acc[r][h];
        }
    }
}

// ---------------------------------------------------------------------------
// softmax over s (2048) per (b,h); reduces 4 c-chunk partials, scale 1/sqrt(512)
// ---------------------------------------------------------------------------
__global__ __launch_bounds__(256) void softmax_k(
    const float* __restrict__ part, float* __restrict__ attn) {
    __shared__ float sc[4];
    int bh = blockIdx.x, tid = threadIdx.x;
    float v[8];
    float mx = -1e30f;
#pragma unroll
    for (int k = 0; k < 8; k++) {
        int s = tid + k * 256;
        float x = 0.f;
        for (int cc = 0; cc < 4; cc++) x += part[((size_t)(cc * 64 + bh)) * 2048 + s];
        x *= 0.04419417382415922f; // 1/sqrt(512)
        v[k] = x;
        mx = fmaxf(mx, x);
    }
    float M = block_max256(mx, sc);
    float sum = 0.f;
#pragma unroll
    for (int k = 0; k < 8; k++) { v[k] = expf(v[k] - M); sum += v[k]; }
    float Sv = block_sum256(sum, sc);
    float inv = 1.f / Sv;
#pragma unroll
    for (int k = 0; k < 8; k++) attn[(size_t)bh * 2048 + tid + k * 256] = v[k] * inv;
}

// ---------------------------------------------------------------------------
// pooled_part[sc][b][h][j] = sum_{s in chunk of 128} attn[b,h,s] * llm[b,s,j]
// grid (4 jb, 16 sc, 8 b)
// ---------------------------------------------------------------------------
__global__ __launch_bounds__(256) void pooled_k(
    const float* __restrict__ llm, const float* __restrict__ attn,
    float* __restrict__ part) {
    __shared__ float alds[1024]; // 8 h x 128 s
    int tid = threadIdx.x;
    int jb = blockIdx.x, sc = blockIdx.y, b = blockIdx.z;
    for (int idx = tid; idx < 1024; idx += 256) {
        int h = idx >> 7, sl = idx & 127;
        alds[idx] = attn[((size_t)(b * 8 + h)) * 2048 + sc * 128 + sl];
    }
    __syncthreads();
    int j = jb * 1024 + tid * 4;
    const float* lbase = llm + ((size_t)(b * 2048 + sc * 128)) * 4096 + j;
    float acc[8][4] = {};
    for (int si = 0; si < 128; si += 8) {
        float4 lv[8];
#pragma unroll
        for (int u = 0; u < 8; u++) lv[u] = *(const float4*)(lbase + (size_t)(si + u) * 4096);
#pragma unroll
        for (int u = 0; u < 8; u++)
#pragma unroll
            for (int h = 0; h < 8; h++) {
                float a = alds[h * 128 + si + u];
                acc[h][0] = fmaf(a, lv[u].x, acc[h][0]);
                acc[h][1] = fmaf(a, lv[u].y, acc[h][1]);
                acc[h][2] = fmaf(a, lv[u].z, acc[h][2]);
                acc[h][3] = fmaf(a, lv[u].w, acc[h][3]);
            }
    }
#pragma unroll
    for (int h = 0; h < 8; h++) {
        float4 o; o.x = acc[h][0]; o.y = acc[h][1]; o.z = acc[h][2]; o.w = acc[h][3];
        *(float4*)(part + ((size_t)(sc * 8 + b) * 8 + h) * 4096 + j) = o;
    }
}

// ---------------------------------------------------------------------------
// ctx_part[ic][b][j] = sum_{i in chunk 64} pooled[b, h(j), i] * wv[i][j]
// Staging fuses the 16-way pooled-partial reduction (pooled never materialized).
// grid (4 jb, 64 ic); block covers 2 heads.
// ---------------------------------------------------------------------------
__global__ __launch_bounds__(256) void ctx_k(
    const float* __restrict__ ppart, const float* __restrict__ wv,
    float* __restrict__ part) {
    __shared__ float plds[1024]; // [b][hh][ii] = 8*2*64
    int tid = threadIdx.x, jb = blockIdx.x, ic = blockIdx.y;
    int i0 = ic * 64, h0 = jb * 2;
    for (int idx = tid; idx < 1024; idx += 256) {
        int b = idx >> 7, r = idx & 127, hh = r >> 6, ii = r & 63;
        float s = 0.f;
#pragma unroll 4
        for (int sc = 0; sc < 16; sc++)
            s += ppart[((size_t)(sc * 8 + b) * 8 + h0 + hh) * 4096 + i0 + ii];
        plds[(b * 2 + hh) * 64 + ii] = s;
    }
    __syncthreads();
    int j = jb * 1024 + tid * 4;
    int hh = tid >> 7;
    float acc[8][4] = {};
    for (int ii = 0; ii < 64; ii += 8) {
        float4 w[8];
#pragma unroll
        for (int u = 0; u < 8; u++) w[u] = *(const float4*)(wv + (size_t)(i0 + ii + u) * 4096 + j);
#pragma unroll
        for (int u = 0; u < 8; u++)
#pragma unroll
            for (int b = 0; b < 8; b++) {
                float v = plds[(b * 2 + hh) * 64 + ii + u];
                acc[b][0] = fmaf(v, w[u].x, acc[b][0]);
                acc[b][1] = fmaf(v, w[u].y, acc[b][1]);
                acc[b][2] = fmaf(v, w[u].z, acc[b][2]);
                acc[b][3] = fmaf(v, w[u].w, acc[b][3]);
            }
    }
#pragma unroll
    for (int b = 0; b < 8; b++) {
        float4 o; o.x = acc[b][0]; o.y = acc[b][1]; o.z = acc[b][2]; o.w = acc[b][3];
        *(float4*)(part + ((size_t)ic * 8 + b) * 4096 + j) = o;
    }
}

// ---------------------------------------------------------------------------
// LayerNorm over N per row b
// ---------------------------------------------------------------------------
__global__ __launch_bounds__(256) void ln_k(
    const float* __restrict__ x, const float* __restrict__ g,
    const float* __restrict__ be, float* __restrict__ out, int N) {
    __shared__ float sc[4];
    int b = blockIdx.x, tid = threadIdx.x;
    const float* xb = x + (size_t)b * N;
    float s = 0.f, s2 = 0.f;
    for (int i = tid; i < N; i += 256) { float v = xb[i]; s += v; s2 += v * v; }
    s = block_sum256(s, sc);
    s2 = block_sum256(s2, sc);
    float mean = s / N;
    float var = s2 / N - mean * mean;
    float rstd = rsqrtf(var + 1e-5f);
    float* ob = out + (size_t)b * N;
    for (int i = tid; i < N; i += 256) {
        float v = xb[i];
        ob[i] = (v - mean) * rstd * g[i] + be[i];
    }
}

// ---------------------------------------------------------------------------
// Fourier features + cond MLP (tiny, 1 block)
// ---------------------------------------------------------------------------
__global__ __launch_bounds__(256) void cond_k(
    const float* __restrict__ time, const float* __restrict__ four_w,
    const float* __restrict__ w1, const float* __restrict__ b1,
    const float* __restrict__ w2, const float* __restrict__ b2,
    float* __restrict__ cond) {
    __shared__ float ffl[256]; // [b][32]
    __shared__ float c1[512];  // [b][64]
    int tid = threadIdx.x;
    {
        int b = tid >> 5, jj = tid & 31;
        float f = 6.283185307179586f * time[b] * four_w[jj & 15];
        ffl[tid] = (jj < 16) ? cosf(f) : sinf(f);
    }
    __syncthreads();
    for (int idx = tid; idx < 512; idx += 256) {
        int b = idx >> 6, jj = idx & 63;
        float s = b1[jj];
        for (int i = 0; i < 32; i++) s = fmaf(ffl[b * 32 + i], w1[i * 64 + jj], s);
        c1[idx] = swish_f(s);
    }
    __syncthreads();
    {
        int b = tid >> 5, jj = tid & 31;
        float s = b2[jj];
        for (int i = 0; i < 64; i++) s = fmaf(c1[b * 64 + i], w2[i * 32 + jj], s);
        cond[b * 32 + jj] = s;
    }
}

// ---------------------------------------------------------------------------
// rin projection, concat input [cond(32), pfinal(4096), noisy(7)]; chunk 64
// ---------------------------------------------------------------------------
__global__ __launch_bounds__(256) void rin_k(
    const float* __restrict__ cond, const float* __restrict__ pfinal,
    const float* __restrict__ noisy, const float* __restrict__ W,
    float* __restrict__ part) {
    __shared__ float lds[512]; // 8 x 64
    int tid = threadIdx.x, ic = blockIdx.x;
    int i0 = ic * 64;
    int cnt = min(64, 4135 - i0);
    for (int idx = tid; idx < 8 * cnt; idx += 256) {
        int b = idx / cnt, ii = idx - b * cnt;
        int i = i0 + ii;
        float v;
        if (i < 32) v = cond[b * 32 + i];
        else if (i < 4128) v = pfinal[(size_t)b * 4096 + i - 32];
        else v = noisy[b * 7 + i - 4128];
        lds[b * 64 + ii] = v;
    }
    __syncthreads();
    int j = tid;
    float acc[8] = {};
#pragma unroll 4
    for (int ii = 0; ii < cnt; ii++) {
        float w = W[(size_t)(i0 + ii) * 256 + j];
#pragma unroll
        for (int b = 0; b < 8; b++) acc[b] = fmaf(lds[b * 64 + ii], w, acc[b]);
    }
#pragma unroll
    for (int b = 0; b < 8; b++) part[((size_t)ic * 8 + b) * 256 + j] = acc[b];
}

// ---------------------------------------------------------------------------
// Resblock stage 1: g1[b][j] = swish( LN(x)[b,:] . W1[:,j] + b1[j] )
// grid 16 blocks x 256 thr; block jb covers j = jb*64..+63; 4 i-groups of 64.
// ---------------------------------------------------------------------------
__global__ __launch_bounds__(256) void rb1_k(
    const float* __restrict__ xin, const float* __restrict__ g,
    const float* __restrict__ be, const float* __restrict__ W1,
    const float* __restrict__ b1, float* __restrict__ g1) {
    __shared__ float xn[2048];
    __shared__ float red[2048];
    __shared__ float sm[8], sv[8];
    int tid = threadIdx.x, jb = blockIdx.x;
    int b = tid >> 5, l = tid & 31;
    float xv[8];
    float s = 0.f, s2 = 0.f;
#pragma unroll
    for (int k = 0; k < 8; k++) {
        float v = xin[tid * 8 + k];
        xv[k] = v; s += v; s2 += v * v;
    }
    for (int o = 16; o > 0; o >>= 1) { s += __shfl_down(s, o, 32); s2 += __shfl_down(s2, o, 32); }
    if (l == 0) { sm[b] = s; sv[b] = s2; }
    __syncthreads();
    float mean = sm[b] / 256.f;
    float rstd = rsqrtf(sv[b] / 256.f - mean * mean + 1e-5f);
#pragma unroll
    for (int k = 0; k < 8; k++) {
        int i = (tid * 8 + k) & 255;
        xn[tid * 8 + k] = (xv[k] - mean) * rstd * g[i] + be[i];
    }
    __syncthreads();
    int jj = tid & 63, ig = tid >> 6;
    int j = jb * 64 + jj;
    float acc[8] = {};
    for (int i = ig * 64; i < ig * 64 + 64; i += 4) {
        float w[4];
#pragma unroll
        for (int u = 0; u < 4; u++) w[u] = W1[(size_t)(i + u) * 1024 + j];
#pragma unroll
        for (int u = 0; u < 4; u++)
#pragma unroll
            for (int bb = 0; bb < 8; bb++) acc[bb] = fmaf(xn[bb * 256 + i + u], w[u], acc[bb]);
    }
#pragma unroll
    for (int bb = 0; bb < 8; bb++) red[tid * 8 + bb] = acc[bb];
    __syncthreads();
#pragma unroll
    for (int t = 0; t < 2; t++) {
        int idx = tid * 2 + t;           // 512 outputs: jj(64) x b(8)
        int ojj = idx >> 3, ob = idx & 7;
        float v = red[ojj * 8 + ob] + red[512 + ojj * 8 + ob] +
                  red[1024 + ojj * 8 + ob] + red[1536 + ojj * 8 + ob];
        v += b1[jb * 64 + ojj];
        g1[(size_t)ob * 1024 + jb * 64 + ojj] = swish_f(v);
    }
}

// ---------------------------------------------------------------------------
// Resblock stage 2: xout[b][j] = xin[b][j] + g1[b,:] . W2[:,j] + b2[j]
// grid 16 blocks x 256 thr; block jb covers j = jb*16..+15; 16 i-groups of 64.
// ---------------------------------------------------------------------------
__global__ __launch_bounds__(256) void rb2_k(
    const float* __restrict__ g1, const float* __restrict__ W2,
    const float* __restrict__ b2, const float* __restrict__ xres,
    float* __restrict__ xout) {
    __shared__ float gl[8192]; // [b][1024], 32 KB
    __shared__ float red[2048];
    int tid = threadIdx.x, jb = blockIdx.x;
    for (int idx = tid * 4; idx < 8192; idx += 1024)
        *(float4*)&gl[idx] = *(const float4*)&g1[idx];
    __syncthreads();
    int jj = tid & 15, ig = tid >> 4;
    int j = jb * 16 + jj;
    float acc[8] = {};
    for (int i = ig * 64; i < ig * 64 + 64; i += 4) {
        float w[4];
#pragma unroll
        for (int u = 0; u < 4; u++) w[u] = W2[(size_t)(i + u) * 256 + j];
#pragma unroll
        for (int u = 0; u < 4; u++)
#pragma unroll
            for (int bb = 0; bb < 8; bb++) acc[bb] = fmaf(gl[bb * 1024 + i + u], w[u], acc[bb]);
    }
#pragma unroll
    for (int bb = 0; bb < 8; bb++) red[tid * 8 + bb] = acc[bb];
    __syncthreads();
    if (tid < 128) {                      // 128 outputs: jj(16) x b(8)
        int ojj = tid >> 3, ob = tid & 7;
        float v = 0.f;
#pragma unroll
        for (int ig2 = 0; ig2 < 16; ig2++) v += red[(ig2 * 16 + ojj) * 8 + ob];
        int oj = jb * 16 + ojj;
        xout[(size_t)ob * 256 + oj] = v + b2[oj] + xres[(size_t)ob * 256 + oj];
    }
}

// ---------------------------------------------------------------------------
// final: out[b][a] = swish(x3[b,:]) . out_w[:,a] + out_b[a]   (1 block)
// ---------------------------------------------------------------------------
__global__ __launch_bounds__(256) void final_k(
    const float* __restrict__ x3, const float* __restrict__ out_w,
    const float* __restrict__ out_b, float* __restrict__ out) {
    __shared__ float sw[2048];
    int tid = threadIdx.x;
    for (int idx = tid; idx < 2048; idx += 256) sw[idx] = swish_f(x3[idx]);
    __syncthreads();
    if (tid < 56) {
        int b = tid / 7, a = tid - b * 7;
        float s = out_b[a];
        for (int i = 0; i < 256; i++) s = fmaf(sw[b * 256 + i], out_w[i * 7 + a], s);
        out[tid] = s;
    }
}

// ---------------------------------------------------------------------------
extern "C" void kernel_launch(void* const* d_in, const int* in_sizes, int n_in,
                              void* d_out, int out_size, void* d_ws, size_t ws_size,
                              hipStream_t stream) {
    const float* llm     = (const float*)d_in[0];
    const float* time_   = (const float*)d_in[1];
    const float* noisy   = (const float*)d_in[2];
    const float* probe   = (const float*)d_in[3];
    const float* wq      = (const float*)d_in[4];
    const float* wk      = (const float*)d_in[5];
    const float* wv      = (const float*)d_in[6];
    const float* bq      = (const float*)d_in[7];
    // d_in[8] = bk: cancels exactly in softmax — unused.
    const float* bv      = (const float*)d_in[9];
    const float* wo      = (const float*)d_in[10];
    const float* bo      = (const float*)d_in[11];
    const float* ln_g    = (const float*)d_in[12];
    const float* ln_b    = (const float*)d_in[13];
    const float* mlp_w1  = (const float*)d_in[14];
    const float* mlp_b1  = (const float*)d_in[15];
    const float* mlp_w2  = (const float*)d_in[16];
    const float* mlp_b2  = (const float*)d_in[17];
    const float* four_w  = (const float*)d_in[18];
    const float* cond_w1 = (const float*)d_in[19];
    const float* cond_b1 = (const float*)d_in[20];
    const float* cond_w2 = (const float*)d_in[21];
    const float* cond_b2 = (const float*)d_in[22];
    const float* rin_w   = (const float*)d_in[23];
    const float* rin_b   = (const float*)d_in[24];
    const float* bln_g   = (const float*)d_in[25];
    const float* bln_b   = (const float*)d_in[26];
    const float* bw1     = (const float*)d_in[27];
    const float* bb1     = (const float*)d_in[28];
    const float* bw2     = (const float*)d_in[29];
    const float* bb2     = (const float*)d_in[30];
    const float* out_w   = (const float*)d_in[31];
    const float* out_b   = (const float*)d_in[32];

    float* ws = (float*)d_ws;
    const size_t A = (size_t)4 * 1024 * 1024; // 16 MB arena (floats)
    float* arena    = ws;
    float* arena2   = ws + A;            // 8 MB secondary partial arena
    float* q        = arena2 + 2097152;  // 4096
    float* qw       = q + 4096;          // 8*4096
    float* attn     = qw + 32768;        // 8*8*2048
    float* ctx      = attn + 131072;     // 8*4096
    float* attn_out = ctx + 32768;       // 8*4096
    float* y        = attn_out + 32768;  // 8*4096
    float* h1a      = y + 32768;         // 8*16384
    float* pfinal   = h1a + 131072;      // 8*4096
    float* cond     = pfinal + 32768;    // 8*32
    float* x0       = cond + 256;        // 8*256
    float* g1a      = x0 + 2048;         // 8*1024
    float* x1       = g1a + 8192;
    float* x2       = x1 + 2048;
    float* x3       = x2 + 2048;

    // ---- MAPHead ----
    gemvp_k<1><<<dim3(4, 64), 256, 64 * 4, stream>>>(probe, wq, arena, 4096, 4096, 64);
    reduce_k<<<16, 256, 0, stream>>>(arena, bq, nullptr, q, 4096, 4096, 64, 0);
    qw_k<<<8192, 256, 0, stream>>>(q, wk, qw);
    scores_k<<<dim3(1024, 4), 256, 0, stream>>>(llm, qw, arena);         // llm pass 1
    softmax_k<<<64, 256, 0, stream>>>(arena, attn);
    pooled_k<<<dim3(4, 16, 8), 256, 0, stream>>>(llm, attn, arena);      // llm pass 2
    ctx_k<<<dim3(4, 64), 256, 0, stream>>>(arena, wv, arena2);           // fused pooled-reduce
    reduce_k<<<32, 256, 0, stream>>>(arena2, bv, nullptr, ctx, 32768, 4096, 64, 0);
    gemvp_k<8><<<dim3(4, 64), 256, 8 * 64 * 4, stream>>>(ctx, wo, arena, 4096, 4096, 64);
    reduce_k<<<32, 256, 0, stream>>>(arena, bo, nullptr, attn_out, 32768, 4096, 64, 0);
    ln_k<<<8, 256, 0, stream>>>(attn_out, ln_g, ln_b, y, 4096);
    gemvp_k<8><<<dim3(16, 32), 256, 8 * 128 * 4, stream>>>(y, mlp_w1, arena, 4096, 16384, 128);
    reduce_k<<<256, 256, 0, stream>>>(arena, mlp_b1, nullptr, h1a, 131072, 16384, 32, 1);
    gemvp_k<8><<<dim3(4, 128), 256, 8 * 128 * 4, stream>>>(h1a, mlp_w2, arena, 16384, 4096, 128);
    reduce_k<<<64, 256, 0, stream>>>(arena, mlp_b2, attn_out, pfinal, 32768, 4096, 128, 0);

    // ---- diffusion tail ----
    cond_k<<<1, 256, 0, stream>>>(time_, four_w, cond_w1, cond_b1, cond_w2, cond_b2, cond);
    rin_k<<<65, 256, 0, stream>>>(cond, pfinal, noisy, rin_w, arena);
    reduce_k<<<8, 256, 0, stream>>>(arena, rin_b, nullptr, x0, 2048, 256, 65, 0);

    float* xs[4] = {x0, x1, x2, x3};
    for (int i = 0; i < 3; i++) {
        rb1_k<<<16, 256, 0, stream>>>(xs[i], bln_g + i * 256, bln_b + i * 256,
                                      bw1 + (size_t)i * 256 * 1024, bb1 + i * 1024, g1a);
        rb2_k<<<16, 256, 0, stream>>>(g1a, bw2 + (size_t)i * 1024 * 256, bb2 + i * 256,
                                      xs[i], xs[i + 1]);
    }
    final_k<<<1, 256, 0, stream>>>(x3, out_w, out_b, (float*)d_out);
}